// Round 1
// baseline (695.313 us; speedup 1.0000x reference)
//
#include <hip/hip_runtime.h>

// CRF forward (logZ) + Viterbi (best score + backpointers), chain-latency round.
//
// Grid (B/2, 2): blockIdx.y = role (0 fwd, 1 vit). One wave per block; wave
// covers TWO batches. Lane map (NEW): t0 = l&15, batch = (l>>4)&1,
// tag i = t0 | ((l>>1)&16)  -> each batch's tags split across the two
// 16-rows of its half, partner half reachable by lane^32.
//
// 1 wave/SIMD => wall == per-step dependency chain. This round removes the
// LDS write->barrier->read round trip (~200+ cy) from the chain:
//   * all-to-all within 16 lanes: DPP xor network (quad_perm x1/x2/x3,
//     row_half_mirror=xor7, row_mirror=xor15) -- 15 VALU movs, xor-symmetric
//     so no shift-direction ambiguity.
//   * cross 16<->16 half: 16 ds_bpermute (addr=(l^32)<<2), issued early,
//     consumed after own-half work (latency overlapped).
//   * fwd rescale source q0=p[tag0] lagged one step via one bpermute
//     (uniform-scale identity is exact regardless of which step's uniform
//     value is used; 2-step growth bound ~e^37 << e^88 overflow).
//   * vit: best via exact fmax tree (order-free); ptr via eq-vs-max +
//     min-tree over per-lane TAG registers => exact leftmost-tie semantics
//     (ties at -1e4/-2e4 are real), extraction is off the sc recurrence.
// Viterbi value path bit-exact vs numpy; fwd only reorders the FMA sum.

#define SS 1024
#define BB 1024
#define TT 32
#define POFF (2 * BB)   // pointers offset in d_out (after logZ, best_score)

static __device__ __forceinline__ float fastrcp(float x) {
#if __has_builtin(__builtin_amdgcn_rcpf)
  return __builtin_amdgcn_rcpf(x);
#else
  return 1.0f / x;
#endif
}

#define DPP_QX1   0xB1   // quad_perm [1,0,3,2] : xor 1
#define DPP_QX2   0x4E   // quad_perm [2,3,0,1] : xor 2
#define DPP_QX3   0x1B   // quad_perm [3,2,1,0] : xor 3
#define DPP_RMIR  0x140  // row_mirror        : xor 15 (within 16)
#define DPP_RHMIR 0x141  // row_half_mirror   : xor 7  (within 8)

template <int CTRL>
static __device__ __forceinline__ float dppx(float x) {
  return __int_as_float(
      __builtin_amdgcn_update_dpp(0, __float_as_int(x), CTRL, 0xF, 0xF, false));
}

static __device__ __forceinline__ float bperm(int byteaddr, float x) {
  return __int_as_float(
      __builtin_amdgcn_ds_bpermute(byteaddr, __float_as_int(x)));
}

// r[m][l] = x[lane l ^ m], m = 0..15 (xor within 16-lane rows; VALU-only).
static __device__ __forceinline__ void gather16(float x, float r[16]) {
  r[0]  = x;
  r[1]  = dppx<DPP_QX1>(x);
  r[2]  = dppx<DPP_QX2>(x);
  r[3]  = dppx<DPP_QX3>(x);
  r[7]  = dppx<DPP_RHMIR>(x);
  r[6]  = dppx<DPP_QX1>(r[7]);
  r[5]  = dppx<DPP_QX2>(r[7]);
  r[4]  = dppx<DPP_QX3>(r[7]);
  r[15] = dppx<DPP_RMIR>(x);
  r[14] = dppx<DPP_QX1>(r[15]);
  r[13] = dppx<DPP_QX2>(r[15]);
  r[12] = dppx<DPP_QX3>(r[15]);
  r[8]  = dppx<DPP_RHMIR>(r[15]);
  r[9]  = dppx<DPP_QX1>(r[8]);
  r[10] = dppx<DPP_QX2>(r[8]);
  r[11] = dppx<DPP_QX3>(r[8]);
}

__global__ __launch_bounds__(64, 1) void crf4_kernel(
    const float* __restrict__ feats,
    const float* __restrict__ mask,
    const float* __restrict__ trans,
    float* __restrict__ out) {

  const int l  = threadIdx.x;
  const int t0 = l & 15;
  const int i  = t0 | ((l >> 1) & 16);   // tag
  const int h  = (l >> 4) & 1;           // which batch of the pair
  const int b0 = blockIdx.x * 2;
  const int b  = b0 + h;
  const int bp32 = (l ^ 32) << 2;        // bpermute addr: partner half
  const bool hiHalf = (l & 32) != 0;     // this lane's own tags are 16..31

  const float* fbase = feats + (size_t)b * TT + i;   // + s*BB*TT per step
  const float* mbase = mask + b;                     // + s*BB per step
  const float t_stop = trans[30 * TT + i];           // trans[STOP_TAG][i]

  // 8-step prefetch in two 4-buffers; refills placed right after consumption.
  float fA[4], mA[4], fB[4], mB[4];
#pragma unroll
  for (int u = 0; u < 4; ++u) {
    fA[u] = fbase[(size_t)u * (BB * TT)];
    mA[u] = mbase[(size_t)u * BB];
    fB[u] = fbase[(size_t)(u + 4) * (BB * TT)];
    mB[u] = mbase[(size_t)(u + 4) * BB];
  }

  if (blockIdx.y == 0) {
    // ======================= forward (logZ) =======================
    // slot m: own-half source tag jown = hiHalf ? 16|(t0^m) : (t0^m),
    //         other-half source tag joth = complement. exp(-10000) == 0.
    float eOwn[16], eOth[16];
#pragma unroll
    for (int m = 0; m < 16; ++m) {
      int x = t0 ^ m;
      int jown = hiHalf ? (16 | x) : x;
      int joth = hiHalf ? x : (16 | x);
      eOwn[m] = __expf(trans[i * TT + jown]);
      eOth[m] = __expf(trans[i * TT + joth]);
    }

    float p   = (i == 29) ? 1.0f : 0.0f;   // exp(alpha0), START_TAG = 29
    float C   = 0.0f;
    float q0f = 0.0f;                      // lagged p[tag0] (init: tag0 != START)

    auto fstep = [&](float fv, float mv) {
      bool act = (mv != 0.0f);
      float ef = __expf(fv);               // off-chain (load-dependent only)
      float r16[16];
      gather16(p, r16);
      float oth[16];
#pragma unroll
      for (int m = 0; m < 16; ++m) oth[m] = bperm(bp32, r16[m]);  // issue early
      float a0 = eOwn[0] * r16[0], a1 = eOwn[1] * r16[1];
      float a2 = eOwn[2] * r16[2], a3 = eOwn[3] * r16[3];
#pragma unroll
      for (int m = 4; m < 16; m += 4) {    // own half first: no lgkm wait
        a0 = fmaf(eOwn[m + 0], r16[m + 0], a0);
        a1 = fmaf(eOwn[m + 1], r16[m + 1], a1);
        a2 = fmaf(eOwn[m + 2], r16[m + 2], a2);
        a3 = fmaf(eOwn[m + 3], r16[m + 3], a3);
      }
#pragma unroll
      for (int m = 0; m < 16; m += 4) {    // partner half (bpermute results)
        a0 = fmaf(eOth[m + 0], oth[m + 0], a0);
        a1 = fmaf(eOth[m + 1], oth[m + 1], a1);
        a2 = fmaf(eOth[m + 2], oth[m + 2], a2);
        a3 = fmaf(eOth[m + 3], oth[m + 3], a3);
      }
      float D   = (a0 + a1) + (a2 + a3);
      float q0c = fmaxf(q0f, 1e-20f);      // uniform per batch (lagged 1 step)
      float r   = fastrcp(q0c);
      float pn  = D * r * ef;
      p = act ? pn : p;
      C += act ? __logf(q0c) : 0.0f;       // off-chain (epilogue-only)
      q0f = bperm((l & 16) << 2, p);       // broadcast tag0 -> next step
    };

#pragma unroll 1
    for (int s = 0; s < SS; s += 8) {
      if (__ballot(mA[0] != 0.0f) == 0ull) goto fwd_done;  // monotone mask
#pragma unroll
      for (int u = 0; u < 4; ++u) fstep(fA[u], mA[u]);
#pragma unroll
      for (int u = 0; u < 4; ++u) {        // refill A with s+8..s+11
        int su = s + 8 + u; su = (su < SS) ? su : 0;
        fA[u] = fbase[(size_t)su * (BB * TT)];
        mA[u] = mbase[(size_t)su * BB];
      }
      if (__ballot(mB[0] != 0.0f) == 0ull) goto fwd_done;
#pragma unroll
      for (int u = 0; u < 4; ++u) fstep(fB[u], mB[u]);
#pragma unroll
      for (int u = 0; u < 4; ++u) {        // refill B with s+12..s+15
        int su = s + 12 + u; su = (su < SS) ? su : 0;
        fB[u] = fbase[(size_t)su * (BB * TT)];
        mB[u] = mbase[(size_t)su * BB];
      }
    }
fwd_done:
    {
      float alpha = C + __logf(p);         // p==0 -> -inf (dead tags), OK
      float v = alpha + t_stop;
      // batch group = lanes with bit4 fixed: xor set {1,2,4,8,32}
      float M2 = v;
      M2 = fmaxf(M2, __shfl_xor(M2, 1, 64));
      M2 = fmaxf(M2, __shfl_xor(M2, 2, 64));
      M2 = fmaxf(M2, __shfl_xor(M2, 4, 64));
      M2 = fmaxf(M2, __shfl_xor(M2, 8, 64));
      M2 = fmaxf(M2, __shfl_xor(M2, 32, 64));
      float e = __expf(v - M2);
      e += __shfl_xor(e, 1, 64);
      e += __shfl_xor(e, 2, 64);
      e += __shfl_xor(e, 4, 64);
      e += __shfl_xor(e, 8, 64);
      e += __shfl_xor(e, 32, 64);
      if (i == 0) out[b] = M2 + __logf(e);
    }
    return;
  }

  // ========================= viterbi =========================
  {
    float tOwn[16], tOth[16];
    int   gOwn[16], gOth[16];
#pragma unroll
    for (int m = 0; m < 16; ++m) {
      int x = t0 ^ m;
      int jown = hiHalf ? (16 | x) : x;
      int joth = hiHalf ? x : (16 | x);
      tOwn[m] = trans[i * TT + jown];
      tOth[m] = trans[i * TT + joth];
      gOwn[m] = jown;
      gOth[m] = joth;
    }

    float sc = (i == 29) ? 0.0f : -10000.0f;
    int s_exit = SS;
    float* outp = out + POFF + (size_t)b * TT + i;

    auto vstep = [&](float& best, int& ptr) {
      float r16[16];
      gather16(sc, r16);
      float vv[32];
#pragma unroll
      for (int m = 0; m < 16; ++m) vv[16 + m] = bperm(bp32, r16[m]) + tOth[m];
#pragma unroll
      for (int m = 0; m < 16; ++m) vv[m] = r16[m] + tOwn[m];
      // exact max: own-half tree first (overlaps bpermute latency)
      float w0[8], w1[8];
#pragma unroll
      for (int k = 0; k < 8; ++k) w0[k] = fmaxf(vv[k], vv[k + 8]);
#pragma unroll
      for (int st = 4; st >= 1; st >>= 1)
#pragma unroll
        for (int k = 0; k < st; ++k) w0[k] = fmaxf(w0[k], w0[k + st]);
#pragma unroll
      for (int k = 0; k < 8; ++k) w1[k] = fmaxf(vv[16 + k], vv[24 + k]);
#pragma unroll
      for (int st = 4; st >= 1; st >>= 1)
#pragma unroll
        for (int k = 0; k < st; ++k) w1[k] = fmaxf(w1[k], w1[k + st]);
      float mx = fmaxf(w0[0], w1[0]);
      // leftmost argmax: min TAG among slots equal to the exact max
      int ix[32];
#pragma unroll
      for (int m = 0; m < 16; ++m) {
        ix[m]      = (vv[m]      == mx) ? gOwn[m] : 63;
        ix[16 + m] = (vv[16 + m] == mx) ? gOth[m] : 63;
      }
      int u[16];
#pragma unroll
      for (int k = 0; k < 16; ++k) u[k] = (ix[k] < ix[k + 16]) ? ix[k] : ix[k + 16];
#pragma unroll
      for (int st = 8; st >= 1; st >>= 1)
#pragma unroll
        for (int k = 0; k < st; ++k) u[k] = (u[k] < u[k + st]) ? u[k] : u[k + st];
      best = mx;
      ptr  = u[0];
    };

#pragma unroll 1
    for (int s = 0; s < SS; s += 8) {
      if (__ballot(mA[0] != 0.0f) == 0ull) { s_exit = s; goto vtail; }
#pragma unroll
      for (int u2 = 0; u2 < 4; ++u2) {
        float best; int ptr;
        vstep(best, ptr);
        outp[(size_t)(s + u2) * (BB * TT)] = (float)ptr;
        sc = (mA[u2] != 0.0f) ? (best + fA[u2]) : sc;  // bit-exact vs numpy
      }
#pragma unroll
      for (int u2 = 0; u2 < 4; ++u2) {
        int su = s + 8 + u2; su = (su < SS) ? su : 0;
        fA[u2] = fbase[(size_t)su * (BB * TT)];
        mA[u2] = mbase[(size_t)su * BB];
      }
      if (__ballot(mB[0] != 0.0f) == 0ull) { s_exit = s + 4; goto vtail; }
#pragma unroll
      for (int u2 = 0; u2 < 4; ++u2) {
        float best; int ptr;
        vstep(best, ptr);
        outp[(size_t)(s + 4 + u2) * (BB * TT)] = (float)ptr;
        sc = (mB[u2] != 0.0f) ? (best + fB[u2]) : sc;
      }
#pragma unroll
      for (int u2 = 0; u2 < 4; ++u2) {
        int su = s + 12 + u2; su = (su < SS) ? su : 0;
        fB[u2] = fbase[(size_t)su * (BB * TT)];
        mB[u2] = mbase[(size_t)su * BB];
      }
    }
vtail:
    {
      // frozen scores -> constant ptr rows: compute once, store-only loop
      float tb; int tp;
      vstep(tb, tp);
      float tj = (float)tp;
      for (int s2 = s_exit; s2 < SS; ++s2)
        outp[(size_t)s2 * (BB * TT)] = tj;

      float w = sc + t_stop;
      w = fmaxf(w, __shfl_xor(w, 1, 64));
      w = fmaxf(w, __shfl_xor(w, 2, 64));
      w = fmaxf(w, __shfl_xor(w, 4, 64));
      w = fmaxf(w, __shfl_xor(w, 8, 64));
      w = fmaxf(w, __shfl_xor(w, 32, 64));
      if (i == 0) out[BB + b] = w;
    }
  }
}

extern "C" void kernel_launch(void* const* d_in, const int* in_sizes, int n_in,
                              void* d_out, int out_size, void* d_ws, size_t ws_size,
                              hipStream_t stream) {
  const float* feats = (const float*)d_in[0];
  const float* msk   = (const float*)d_in[1];
  const float* trans = (const float*)d_in[2];
  float* out = (float*)d_out;
  (void)in_sizes; (void)n_in; (void)out_size; (void)d_ws; (void)ws_size;
  crf4_kernel<<<dim3(BB / 2, 2), dim3(64), 0, stream>>>(feats, msk, trans, out);
}

// Round 2
// 631.057 us; speedup vs baseline: 1.1018x; 1.1018x over previous
//
#include <hip/hip_runtime.h>

// CRF forward (logZ) + Viterbi (best score + backpointers).
//
// Grid (B/2, 2): blockIdx.y = role (0 fwd, 1 vit). One wave per block; wave
// covers TWO batches. Lane map (r1-verified): t0 = l&15, batch h = (l>>4)&1,
// tag i = t0 | ((l>>1)&16); partner half of a batch is lane^32.
//
// r1 lesson: 16 ds_bpermute per step (LDS pipe) regressed vs the LDS b128
// round trip. This round the all-gather is PURE VALU:
//   * within 16 lanes: DPP xor network (15 v_mov_dpp, r1-verified).
//   * cross half: ONE v_permlane32_swap_b32 (VALU) + cndmask, then the same
//     15-DPP tree on the swapped base. Zero LDS-pipe ops in viterbi;
//     fwd keeps only the single lagged q0f bpermute (off-chain).
//   * vit argmax: bitmask (msk |= vv==mx ? 1<<tag : 0) + ffs -> exact
//     leftmost-tie (min tag), ~45 ops, off the sc recurrence.
//   * vit max: 3-ary fmaxf nesting -> v_max3_f32 (31 -> 17 ops).
//   * fwd: scale = rcp(q0c)*ef folded off-chain; recurrence tail = 1 mul.
// Viterbi value path bit-exact vs numpy (same adds, order-free exact max,
// leftmost ties); fwd only reorders the FMA sum / scale rounding.

#define SS 1024
#define BB 1024
#define TT 32
#define POFF (2 * BB)   // pointers offset in d_out (after logZ, best_score)

static __device__ __forceinline__ float fastrcp(float x) {
#if __has_builtin(__builtin_amdgcn_rcpf)
  return __builtin_amdgcn_rcpf(x);
#else
  return 1.0f / x;
#endif
}

#define DPP_QX1   0xB1   // quad_perm [1,0,3,2] : xor 1
#define DPP_QX2   0x4E   // quad_perm [2,3,0,1] : xor 2
#define DPP_QX3   0x1B   // quad_perm [3,2,1,0] : xor 3
#define DPP_RMIR  0x140  // row_mirror        : xor 15 (within 16)
#define DPP_RHMIR 0x141  // row_half_mirror   : xor 7  (within 8)

template <int CTRL>
static __device__ __forceinline__ float dppx(float x) {
  return __int_as_float(
      __builtin_amdgcn_update_dpp(0, __float_as_int(x), CTRL, 0xF, 0xF, false));
}

static __device__ __forceinline__ float bperm(int byteaddr, float x) {
  return __int_as_float(
      __builtin_amdgcn_ds_bpermute(byteaddr, __float_as_int(x)));
}

// y[l] = x[l ^ 32] via one v_permlane32_swap_b32 (VALU pipe).
// swap semantics with a=b=x: new_a = {x_lo | x_lo}, new_b = {x_hi | x_hi}
// => hi lanes take r[0] (=x[l-32]), lo lanes take r[1] (=x[l+32]).
static __device__ __forceinline__ float swap32(float x, bool hiHalf) {
#if __has_builtin(__builtin_amdgcn_permlane32_swap)
  auto r = __builtin_amdgcn_permlane32_swap(__float_as_uint(x),
                                            __float_as_uint(x), false, false);
  return __uint_as_float(hiHalf ? r[0] : r[1]);
#else
  float a = x, b = x;
  asm("s_nop 1\n\ts_nop 1\n\tv_permlane32_swap_b32 %0, %1"
      : "+v"(a), "+v"(b));
  return hiHalf ? a : b;
#endif
}

// r[m][l] = x[lane l ^ m], m = 0..15 (xor within 16-lane rows; VALU-only).
static __device__ __forceinline__ void gather16(float x, float r[16]) {
  r[0]  = x;
  r[1]  = dppx<DPP_QX1>(x);
  r[2]  = dppx<DPP_QX2>(x);
  r[3]  = dppx<DPP_QX3>(x);
  r[7]  = dppx<DPP_RHMIR>(x);
  r[6]  = dppx<DPP_QX1>(r[7]);
  r[5]  = dppx<DPP_QX2>(r[7]);
  r[4]  = dppx<DPP_QX3>(r[7]);
  r[15] = dppx<DPP_RMIR>(x);
  r[14] = dppx<DPP_QX1>(r[15]);
  r[13] = dppx<DPP_QX2>(r[15]);
  r[12] = dppx<DPP_QX3>(r[15]);
  r[8]  = dppx<DPP_RHMIR>(r[15]);
  r[9]  = dppx<DPP_QX1>(r[8]);
  r[10] = dppx<DPP_QX2>(r[8]);
  r[11] = dppx<DPP_QX3>(r[8]);
}

__global__ __launch_bounds__(64, 1) void crf5_kernel(
    const float* __restrict__ feats,
    const float* __restrict__ mask,
    const float* __restrict__ trans,
    float* __restrict__ out) {

  const int l  = threadIdx.x;
  const int t0 = l & 15;
  const int i  = t0 | ((l >> 1) & 16);   // tag
  const int h  = (l >> 4) & 1;           // which batch of the pair
  const int b0 = blockIdx.x * 2;
  const int b  = b0 + h;
  const bool hiHalf = (l & 32) != 0;     // this lane's own tags are 16..31

  const float* fbase = feats + (size_t)b * TT + i;   // + s*BB*TT per step
  const float* mbase = mask + b;                     // + s*BB per step
  const float t_stop = trans[30 * TT + i];           // trans[STOP_TAG][i]

  // 8-step prefetch in two 4-buffers; refills placed right after consumption.
  float fA[4], mA[4], fB[4], mB[4];
#pragma unroll
  for (int u = 0; u < 4; ++u) {
    fA[u] = fbase[(size_t)u * (BB * TT)];
    mA[u] = mbase[(size_t)u * BB];
    fB[u] = fbase[(size_t)(u + 4) * (BB * TT)];
    mB[u] = mbase[(size_t)(u + 4) * BB];
  }

  if (blockIdx.y == 0) {
    // ======================= forward (logZ) =======================
    // slot m: own-half source tag jown = hiHalf ? 16|(t0^m) : (t0^m),
    //         other-half source tag joth = complement. exp(-10000) == 0.
    float eOwn[16], eOth[16];
#pragma unroll
    for (int m = 0; m < 16; ++m) {
      int x = t0 ^ m;
      int jown = hiHalf ? (16 | x) : x;
      int joth = hiHalf ? x : (16 | x);
      eOwn[m] = __expf(trans[i * TT + jown]);
      eOth[m] = __expf(trans[i * TT + joth]);
    }

    float p   = (i == 29) ? 1.0f : 0.0f;   // exp(alpha0), START_TAG = 29
    float C   = 0.0f;
    float q0f = 0.0f;                      // lagged p[tag0] (init: tag0 != START)

    auto fstep = [&](float fv, float mv) {
      bool act = (mv != 0.0f);
      float ef  = __expf(fv);              // off-chain (load-dependent only)
      float q0c = fmaxf(q0f, 1e-20f);      // uniform per batch (lagged 1 step)
      float scale = fastrcp(q0c) * ef;     // off the p-chain entirely
      float r16[16];
      gather16(p, r16);
      float y = swap32(p, hiHalf);         // VALU cross-half
      float o16[16];
      gather16(y, o16);
      float a0 = eOwn[0] * r16[0], a1 = eOwn[1] * r16[1];
      float a2 = eOwn[2] * r16[2], a3 = eOwn[3] * r16[3];
#pragma unroll
      for (int m = 4; m < 16; m += 4) {
        a0 = fmaf(eOwn[m + 0], r16[m + 0], a0);
        a1 = fmaf(eOwn[m + 1], r16[m + 1], a1);
        a2 = fmaf(eOwn[m + 2], r16[m + 2], a2);
        a3 = fmaf(eOwn[m + 3], r16[m + 3], a3);
      }
#pragma unroll
      for (int m = 0; m < 16; m += 4) {
        a0 = fmaf(eOth[m + 0], o16[m + 0], a0);
        a1 = fmaf(eOth[m + 1], o16[m + 1], a1);
        a2 = fmaf(eOth[m + 2], o16[m + 2], a2);
        a3 = fmaf(eOth[m + 3], o16[m + 3], a3);
      }
      float D  = (a0 + a1) + (a2 + a3);
      float pn = D * scale;                // chain tail: one mul
      p = act ? pn : p;
      C += act ? __logf(q0c) : 0.0f;       // off-chain (epilogue-only)
      q0f = bperm((l & 16) << 2, p);       // broadcast tag0 -> next step
    };

#pragma unroll 1
    for (int s = 0; s < SS; s += 8) {
      if (__ballot(mA[0] != 0.0f) == 0ull) goto fwd_done;  // monotone mask
#pragma unroll
      for (int u = 0; u < 4; ++u) fstep(fA[u], mA[u]);
#pragma unroll
      for (int u = 0; u < 4; ++u) {        // refill A with s+8..s+11
        int su = s + 8 + u; su = (su < SS) ? su : 0;
        fA[u] = fbase[(size_t)su * (BB * TT)];
        mA[u] = mbase[(size_t)su * BB];
      }
      if (__ballot(mB[0] != 0.0f) == 0ull) goto fwd_done;
#pragma unroll
      for (int u = 0; u < 4; ++u) fstep(fB[u], mB[u]);
#pragma unroll
      for (int u = 0; u < 4; ++u) {        // refill B with s+12..s+15
        int su = s + 12 + u; su = (su < SS) ? su : 0;
        fB[u] = fbase[(size_t)su * (BB * TT)];
        mB[u] = mbase[(size_t)su * BB];
      }
    }
fwd_done:
    {
      float alpha = C + __logf(p);         // p==0 -> -inf (dead tags), OK
      float v = alpha + t_stop;
      // batch group = lanes with bit4 fixed: xor set {1,2,4,8,32}
      float M2 = v;
      M2 = fmaxf(M2, __shfl_xor(M2, 1, 64));
      M2 = fmaxf(M2, __shfl_xor(M2, 2, 64));
      M2 = fmaxf(M2, __shfl_xor(M2, 4, 64));
      M2 = fmaxf(M2, __shfl_xor(M2, 8, 64));
      M2 = fmaxf(M2, __shfl_xor(M2, 32, 64));
      float e = __expf(v - M2);
      e += __shfl_xor(e, 1, 64);
      e += __shfl_xor(e, 2, 64);
      e += __shfl_xor(e, 4, 64);
      e += __shfl_xor(e, 8, 64);
      e += __shfl_xor(e, 32, 64);
      if (i == 0) out[b] = M2 + __logf(e);
    }
    return;
  }

  // ========================= viterbi =========================
  {
    float    tOwn[16], tOth[16];
    unsigned bOwn[16], bOth[16];           // 1u << source-tag (for ffs argmax)
#pragma unroll
    for (int m = 0; m < 16; ++m) {
      int x = t0 ^ m;
      int jown = hiHalf ? (16 | x) : x;
      int joth = hiHalf ? x : (16 | x);
      tOwn[m] = trans[i * TT + jown];
      tOth[m] = trans[i * TT + joth];
      bOwn[m] = 1u << jown;
      bOth[m] = 1u << joth;
    }

    float sc = (i == 29) ? 0.0f : -10000.0f;
    int s_exit = SS;
    float* outp = out + POFF + (size_t)b * TT + i;

    auto vstep = [&](float& best, int& ptr) {
      float r16[16];
      gather16(sc, r16);
      float y = swap32(sc, hiHalf);        // VALU cross-half (no LDS pipe)
      float o16[16];
      gather16(y, o16);
      float vv[32];
#pragma unroll
      for (int m = 0; m < 16; ++m) vv[m] = r16[m] + tOwn[m];
#pragma unroll
      for (int m = 0; m < 16; ++m) vv[16 + m] = o16[m] + tOth[m];
      // exact max, 3-ary tree (fmaxf(fmaxf(a,b),c) fuses to v_max3_f32)
      float g[11];
#pragma unroll
      for (int k = 0; k < 10; ++k)
        g[k] = fmaxf(fmaxf(vv[3 * k], vv[3 * k + 1]), vv[3 * k + 2]);
      g[10] = fmaxf(vv[30], vv[31]);
      float h0 = fmaxf(fmaxf(g[0], g[1]), g[2]);
      float h1 = fmaxf(fmaxf(g[3], g[4]), g[5]);
      float h2 = fmaxf(fmaxf(g[6], g[7]), g[8]);
      float h3 = fmaxf(g[9], g[10]);
      float mx = fmaxf(fmaxf(fmaxf(h0, h1), h2), h3);
      // leftmost argmax: bit per source tag, find-first-set => min tag.
      unsigned msk = 0u;
#pragma unroll
      for (int m = 0; m < 16; ++m) msk |= (vv[m] == mx) ? bOwn[m] : 0u;
#pragma unroll
      for (int m = 0; m < 16; ++m) msk |= (vv[16 + m] == mx) ? bOth[m] : 0u;
      best = mx;
      ptr  = __ffs(msk) - 1;
    };

#pragma unroll 1
    for (int s = 0; s < SS; s += 8) {
      if (__ballot(mA[0] != 0.0f) == 0ull) { s_exit = s; goto vtail; }
#pragma unroll
      for (int u2 = 0; u2 < 4; ++u2) {
        float best; int ptr;
        vstep(best, ptr);
        outp[(size_t)(s + u2) * (BB * TT)] = (float)ptr;
        sc = (mA[u2] != 0.0f) ? (best + fA[u2]) : sc;  // bit-exact vs numpy
      }
#pragma unroll
      for (int u2 = 0; u2 < 4; ++u2) {
        int su = s + 8 + u2; su = (su < SS) ? su : 0;
        fA[u2] = fbase[(size_t)su * (BB * TT)];
        mA[u2] = mbase[(size_t)su * BB];
      }
      if (__ballot(mB[0] != 0.0f) == 0ull) { s_exit = s + 4; goto vtail; }
#pragma unroll
      for (int u2 = 0; u2 < 4; ++u2) {
        float best; int ptr;
        vstep(best, ptr);
        outp[(size_t)(s + 4 + u2) * (BB * TT)] = (float)ptr;
        sc = (mB[u2] != 0.0f) ? (best + fB[u2]) : sc;
      }
#pragma unroll
      for (int u2 = 0; u2 < 4; ++u2) {
        int su = s + 12 + u2; su = (su < SS) ? su : 0;
        fB[u2] = fbase[(size_t)su * (BB * TT)];
        mB[u2] = mbase[(size_t)su * BB];
      }
    }
vtail:
    {
      // frozen scores -> constant ptr rows: compute once, store-only loop
      float tb; int tp;
      vstep(tb, tp);
      float tj = (float)tp;
      for (int s2 = s_exit; s2 < SS; ++s2)
        outp[(size_t)s2 * (BB * TT)] = tj;

      float w = sc + t_stop;
      w = fmaxf(w, __shfl_xor(w, 1, 64));
      w = fmaxf(w, __shfl_xor(w, 2, 64));
      w = fmaxf(w, __shfl_xor(w, 4, 64));
      w = fmaxf(w, __shfl_xor(w, 8, 64));
      w = fmaxf(w, __shfl_xor(w, 32, 64));
      if (i == 0) out[BB + b] = w;
    }
  }
}

extern "C" void kernel_launch(void* const* d_in, const int* in_sizes, int n_in,
                              void* d_out, int out_size, void* d_ws, size_t ws_size,
                              hipStream_t stream) {
  const float* feats = (const float*)d_in[0];
  const float* msk   = (const float*)d_in[1];
  const float* trans = (const float*)d_in[2];
  float* out = (float*)d_out;
  (void)in_sizes; (void)n_in; (void)out_size; (void)d_ws; (void)ws_size;
  crf5_kernel<<<dim3(BB / 2, 2), dim3(64), 0, stream>>>(feats, msk, trans, out);
}

// Round 3
// 562.032 us; speedup vs baseline: 1.2371x; 1.1228x over previous
//
#include <hip/hip_runtime.h>

// CRF forward (logZ) + Viterbi (best score + backpointers).
//
// r2 structural change: ONE batch per wave (grid (B,2)) => 2048 waves on
// 1024 SIMDs = 2 waves/SIMD (was 1). The serial-chain latency (DPP hazards,
// dependent VALU, TRANS) is now hidden by the co-resident wave, and per-wave
// per-step issue drops ~40%:
//   lanes: t0=l&15, row=l>>4; tag i=((row&1)<<4)|t0; rows 0,1 = full tag set,
//   rows 2,3 = duplicate copy. Source split: rows 0,3 sum sources 0-15,
//   rows 1,2 sum sources 16-31 => each lane gathers 16 values:
//     * rows 0,1 gather own p within their 16-row (verified 15-DPP xor tree)
//     * rows 2,3 gather z = p[l^16] (one v_permlane16_swap, same
//       dst-high<->src-low convention as the crf5-verified permlane32_swap)
//   then ONE permlane32_swap + add/max merges complementary partials (lane
//   pair l, l^32 holds the same tag).
// One-batch-per-wave bonuses:
//   * mask & rescale are wave-uniform: q0 via readfirstlane -> SGPR.
//   * fwd rescale is EXACT pow2: scale = 2^-(Eb-127) from q0's raw exponent
//     bits; CE accumulates (Eb-127) as an integer (SALU, exact); no rcp/log
//     in the loop. alpha = CE*ln2 + log(p) at the end.
//   * early exit at THIS batch's length (was max of a pair).
// Viterbi value path bit-exact (same adds, exact fmax tree, leftmost ties
// via min-tag among exact-max matches); fwd only reorders the FMA sum.

#define SS 1024
#define BB 1024
#define TT 32
#define POFF (2 * BB)   // pointers offset in d_out (after logZ, best_score)

#define DPP_QX1   0xB1   // quad_perm [1,0,3,2] : xor 1
#define DPP_QX2   0x4E   // quad_perm [2,3,0,1] : xor 2
#define DPP_QX3   0x1B   // quad_perm [3,2,1,0] : xor 3
#define DPP_RMIR  0x140  // row_mirror        : xor 15 (within 16)
#define DPP_RHMIR 0x141  // row_half_mirror   : xor 7  (within 8)

template <int CTRL>
static __device__ __forceinline__ float dppx(float x) {
  return __int_as_float(
      __builtin_amdgcn_update_dpp(0, __float_as_int(x), CTRL, 0xF, 0xF, false));
}

// y[l] = x[l ^ 32]  (VALU pipe; convention verified on HW in crf5)
static __device__ __forceinline__ float swap32(float x, bool hiHalf) {
#if __has_builtin(__builtin_amdgcn_permlane32_swap)
  auto r = __builtin_amdgcn_permlane32_swap(__float_as_uint(x),
                                            __float_as_uint(x), false, false);
  return __uint_as_float(hiHalf ? r[0] : r[1]);
#else
  float a = x, b = x;
  asm("s_nop 1\n\ts_nop 1\n\tv_permlane32_swap_b32 %0, %1"
      : "+v"(a), "+v"(b));
  return hiHalf ? a : b;
#endif
}

// y[l] = x[l ^ 16]  (same dst-high<->src-low convention as swap32)
static __device__ __forceinline__ float swap16(float x, bool hi16) {
#if __has_builtin(__builtin_amdgcn_permlane16_swap)
  auto r = __builtin_amdgcn_permlane16_swap(__float_as_uint(x),
                                            __float_as_uint(x), false, false);
  return __uint_as_float(hi16 ? r[0] : r[1]);
#else
  float a = x, b = x;
  asm("s_nop 1\n\ts_nop 1\n\tv_permlane16_swap_b32 %0, %1"
      : "+v"(a), "+v"(b));
  return hi16 ? a : b;
#endif
}

// r[m][l] = x[lane l ^ m], m = 0..15 (xor within 16-lane rows; VALU-only;
// verified r1/r2 on HW).
static __device__ __forceinline__ void gather16(float x, float r[16]) {
  r[0]  = x;
  r[1]  = dppx<DPP_QX1>(x);
  r[2]  = dppx<DPP_QX2>(x);
  r[3]  = dppx<DPP_QX3>(x);
  r[7]  = dppx<DPP_RHMIR>(x);
  r[6]  = dppx<DPP_QX1>(r[7]);
  r[5]  = dppx<DPP_QX2>(r[7]);
  r[4]  = dppx<DPP_QX3>(r[7]);
  r[15] = dppx<DPP_RMIR>(x);
  r[14] = dppx<DPP_QX1>(r[15]);
  r[13] = dppx<DPP_QX2>(r[15]);
  r[12] = dppx<DPP_QX3>(r[15]);
  r[8]  = dppx<DPP_RHMIR>(r[15]);
  r[9]  = dppx<DPP_QX1>(r[8]);
  r[10] = dppx<DPP_QX2>(r[8]);
  r[11] = dppx<DPP_QX3>(r[8]);
}

__global__ __launch_bounds__(64, 2) void crf6_kernel(
    const float* __restrict__ feats,
    const float* __restrict__ mask,
    const float* __restrict__ trans,
    float* __restrict__ out) {

  const int l   = threadIdx.x;
  const int t0  = l & 15;
  const int row = l >> 4;                      // 0..3
  const int i   = ((row & 1) << 4) | t0;       // tag (rows 2,3 duplicate 0,1)
  const int srcbase = (row == 1 || row == 2) ? 16 : 0;  // this lane's 16 sources
  const bool hi16   = (row & 1) != 0;          // lane bit4
  const bool hiHalf = (row & 2) != 0;          // lane bit5 (rows 2,3 use z)
  const int b = blockIdx.x;

  const float* fbase = feats + (size_t)b * TT + i;   // + s*BB*TT per step
  const float* mbase = mask + b;                     // + s*BB per step (uniform)
  const float t_stop = trans[30 * TT + i];           // trans[STOP_TAG][i]

  // 8-step prefetch in two 4-buffers; refills placed right after consumption.
  float fA[4], mA[4], fB[4], mB[4];
#pragma unroll
  for (int u = 0; u < 4; ++u) {
    fA[u] = fbase[(size_t)u * (BB * TT)];
    mA[u] = mbase[(size_t)u * BB];
    fB[u] = fbase[(size_t)(u + 4) * (BB * TT)];
    mB[u] = mbase[(size_t)(u + 4) * BB];
  }

  if (blockIdx.y == 0) {
    // ======================= forward (logZ) =======================
    float eT[16];
#pragma unroll
    for (int m = 0; m < 16; ++m)
      eT[m] = __expf(trans[i * TT + (srcbase | (t0 ^ m))]);  // exp(-1e4)==0

    float p   = (i == 29) ? 1.0f : 0.0f;   // exp(alpha0), START_TAG = 29
    int   CE  = 0;                         // exact pow2 rescale exponent sum
    float q0f = 1.0f;                      // lagged p[tag0] (any >0 valid)

    auto fstep = [&](float fv, float mv) {
      bool act = (mv != 0.0f);             // wave-uniform
      float ef = __expf(fv);               // off-chain (load-dependent only)
      // exact pow2 scale from lagged q0f's raw exponent: scale = 2^-(Eb-127)
      int Eb = (int)((__float_as_uint(q0f) >> 23) & 0xFFu);
      float scl = __uint_as_float((unsigned)(254 - Eb) << 23);
      float efs = ef * scl;
      float z = swap16(p, hi16);           // rows 2,3 source base
      float basev = hiHalf ? z : p;
      float r16[16];
      gather16(basev, r16);
      float a0 = eT[0] * r16[0], a1 = eT[1] * r16[1];
      float a2 = eT[2] * r16[2], a3 = eT[3] * r16[3];
#pragma unroll
      for (int m = 4; m < 16; m += 4) {
        a0 = fmaf(eT[m + 0], r16[m + 0], a0);
        a1 = fmaf(eT[m + 1], r16[m + 1], a1);
        a2 = fmaf(eT[m + 2], r16[m + 2], a2);
        a3 = fmaf(eT[m + 3], r16[m + 3], a3);
      }
      float Dp = (a0 + a1) + (a2 + a3);    // partial over this lane's 16 srcs
      float Df = Dp + swap32(Dp, hiHalf);  // + complementary partial (l^32)
      float pn = Df * efs;
      p   = act ? pn : p;
      CE += act ? (Eb - 127) : 0;          // integer, exact (SALU)
      q0f = __uint_as_float(
          (unsigned)__builtin_amdgcn_readfirstlane((int)__float_as_uint(p)));
    };

#pragma unroll 1
    for (int s = 0; s < SS; s += 8) {
      if (mA[0] == 0.0f) goto fwd_done;    // uniform monotone mask
#pragma unroll
      for (int u = 0; u < 4; ++u) fstep(fA[u], mA[u]);
#pragma unroll
      for (int u = 0; u < 4; ++u) {        // refill A with s+8..s+11
        int su = s + 8 + u; su = (su < SS) ? su : 0;
        fA[u] = fbase[(size_t)su * (BB * TT)];
        mA[u] = mbase[(size_t)su * BB];
      }
      if (mB[0] == 0.0f) goto fwd_done;
#pragma unroll
      for (int u = 0; u < 4; ++u) fstep(fB[u], mB[u]);
#pragma unroll
      for (int u = 0; u < 4; ++u) {        // refill B with s+12..s+15
        int su = s + 12 + u; su = (su < SS) ? su : 0;
        fB[u] = fbase[(size_t)su * (BB * TT)];
        mB[u] = mbase[(size_t)su * BB];
      }
    }
fwd_done:
    {
      float alpha = (float)CE * 0.693147180559945f + __logf(p);  // p==0 -> -inf
      float v = alpha + t_stop;
      // lanes 0-31 hold all 32 tags (dup in 32-63): xor set {1,2,4,8,16}
      float M2 = v;
      M2 = fmaxf(M2, __shfl_xor(M2, 1, 64));
      M2 = fmaxf(M2, __shfl_xor(M2, 2, 64));
      M2 = fmaxf(M2, __shfl_xor(M2, 4, 64));
      M2 = fmaxf(M2, __shfl_xor(M2, 8, 64));
      M2 = fmaxf(M2, __shfl_xor(M2, 16, 64));
      float e = __expf(v - M2);
      e += __shfl_xor(e, 1, 64);
      e += __shfl_xor(e, 2, 64);
      e += __shfl_xor(e, 4, 64);
      e += __shfl_xor(e, 8, 64);
      e += __shfl_xor(e, 16, 64);
      if (l == 0) out[b] = M2 + __logf(e);
    }
    return;
  }

  // ========================= viterbi =========================
  {
    float tT[16];
    int   tg[16];
#pragma unroll
    for (int m = 0; m < 16; ++m) {
      int j = srcbase | (t0 ^ m);
      tT[m] = trans[i * TT + j];
      tg[m] = j;
    }

    float sc = (i == 29) ? 0.0f : -10000.0f;
    int s_exit = SS;
    float* outp = out + POFF + (size_t)b * TT + i;

    auto vstep = [&](float& best, int& ptr) {
      float z = swap16(sc, hi16);
      float basev = hiHalf ? z : sc;
      float r16[16];
      gather16(basev, r16);
      float vv[16];
#pragma unroll
      for (int m = 0; m < 16; ++m) vv[m] = r16[m] + tT[m];
      // exact max over this lane's 16 (3-ary nesting -> v_max3_f32)
      float g0 = fmaxf(fmaxf(vv[0], vv[1]), vv[2]);
      float g1 = fmaxf(fmaxf(vv[3], vv[4]), vv[5]);
      float g2 = fmaxf(fmaxf(vv[6], vv[7]), vv[8]);
      float g3 = fmaxf(fmaxf(vv[9], vv[10]), vv[11]);
      float g4 = fmaxf(fmaxf(vv[12], vv[13]), vv[14]);
      float h0 = fmaxf(fmaxf(g0, g1), g2);
      float h1 = fmaxf(fmaxf(g3, g4), vv[15]);
      float mxp = fmaxf(h0, h1);
      float mx = fmaxf(mxp, swap32(mxp, hiHalf));  // global over 32 sources
      // leftmost argmax: min source-tag among exact-max matches (off-chain)
      int idx = 63;
#pragma unroll
      for (int m = 0; m < 16; ++m) {
        int cand = (vv[m] == mx) ? tg[m] : 63;
        idx = (cand < idx) ? cand : idx;
      }
      int oidx = __float_as_int(swap32(__int_as_float(idx), hiHalf));
      idx = (oidx < idx) ? oidx : idx;
      best = mx;
      ptr  = idx;
    };

#pragma unroll 1
    for (int s = 0; s < SS; s += 8) {
      if (mA[0] == 0.0f) { s_exit = s; goto vtail; }
#pragma unroll
      for (int u2 = 0; u2 < 4; ++u2) {
        float best; int ptr;
        vstep(best, ptr);
        if (l < 32) outp[(size_t)(s + u2) * (BB * TT)] = (float)ptr;
        sc = (mA[u2] != 0.0f) ? (best + fA[u2]) : sc;  // bit-exact vs numpy
      }
#pragma unroll
      for (int u2 = 0; u2 < 4; ++u2) {
        int su = s + 8 + u2; su = (su < SS) ? su : 0;
        fA[u2] = fbase[(size_t)su * (BB * TT)];
        mA[u2] = mbase[(size_t)su * BB];
      }
      if (mB[0] == 0.0f) { s_exit = s + 4; goto vtail; }
#pragma unroll
      for (int u2 = 0; u2 < 4; ++u2) {
        float best; int ptr;
        vstep(best, ptr);
        if (l < 32) outp[(size_t)(s + 4 + u2) * (BB * TT)] = (float)ptr;
        sc = (mB[u2] != 0.0f) ? (best + fB[u2]) : sc;
      }
#pragma unroll
      for (int u2 = 0; u2 < 4; ++u2) {
        int su = s + 12 + u2; su = (su < SS) ? su : 0;
        fB[u2] = fbase[(size_t)su * (BB * TT)];
        mB[u2] = mbase[(size_t)su * BB];
      }
    }
vtail:
    {
      // frozen scores -> constant ptr rows: compute once, store-only loop
      float tb; int tp;
      vstep(tb, tp);
      float tj = (float)tp;
      for (int s2 = s_exit; s2 < SS; ++s2)
        if (l < 32) outp[(size_t)s2 * (BB * TT)] = tj;

      float w = sc + t_stop;
      w = fmaxf(w, __shfl_xor(w, 1, 64));
      w = fmaxf(w, __shfl_xor(w, 2, 64));
      w = fmaxf(w, __shfl_xor(w, 4, 64));
      w = fmaxf(w, __shfl_xor(w, 8, 64));
      w = fmaxf(w, __shfl_xor(w, 16, 64));
      if (l == 0) out[BB + b] = w;
    }
  }
}

extern "C" void kernel_launch(void* const* d_in, const int* in_sizes, int n_in,
                              void* d_out, int out_size, void* d_ws, size_t ws_size,
                              hipStream_t stream) {
  const float* feats = (const float*)d_in[0];
  const float* msk   = (const float*)d_in[1];
  const float* trans = (const float*)d_in[2];
  float* out = (float*)d_out;
  (void)in_sizes; (void)n_in; (void)out_size; (void)d_ws; (void)ws_size;
  crf6_kernel<<<dim3(BB, 2), dim3(64), 0, stream>>>(feats, msk, trans, out);
}

// Round 4
// 561.127 us; speedup vs baseline: 1.2391x; 1.0016x over previous
//
#include <hip/hip_runtime.h>

// CRF forward (logZ) + Viterbi (best score + backpointers).
//
// Structure (r3-verified): grid (B,2), one batch per wave, 2 waves/SIMD.
// Lanes: t0=l&15, row=l>>4; tag i=((row&1)<<4)|t0; rows 2,3 duplicate tags,
// srcbase: rows 0,3 sum sources 0-15, rows 1,2 sum 16-31; rows 2,3 take
// base from swap16(p); lane pair (l, l^32) holds the same tag with
// complementary source halves, merged by one permlane32_swap.
//
// r3 counters: 970 cy/SIMD-step, VALU 533, dual-wave stall 437. This round:
//   * DPP fused into consumers: gather restructured so 13/15 permutes are
//     single-use leaves feeding v_add/v_fmac directly (GCNDPPCombine ->
//     v_add_f32_dpp / v_fmac_f32_dpp). MAC block: 31 -> ~19 insts.
//   * gather depth 3 -> 2: materialize r7 (xor7), r8 (row_ror:8 == xor8,
//     direction-immune), r15 (xor15); every other mask is one quad-perm
//     from those. Slot values BIT-IDENTICAL to crf6 (pure scheduling).
//   * vit argmax: cmp/cndmask keys + v_min3_u32 tree (exact leftmost-tie:
//     min source tag among exact-max matches), off the sc recurrence.
// fwd rescale exact pow2 (raw exponent, integer CE, SALU); no rcp/log in
// the loop. Viterbi value path bit-exact vs numpy.

#define SS 1024
#define BB 1024
#define TT 32
#define POFF (2 * BB)   // pointers offset in d_out (after logZ, best_score)

#define DPP_QX1   0xB1   // quad_perm [1,0,3,2] : xor 1
#define DPP_QX2   0x4E   // quad_perm [2,3,0,1] : xor 2
#define DPP_QX3   0x1B   // quad_perm [3,2,1,0] : xor 3
#define DPP_RMIR  0x140  // row_mirror        : xor 15 (within 16)
#define DPP_RHMIR 0x141  // row_half_mirror   : xor 7  (within 8)
#define DPP_ROR8  0x128  // row_ror:8         : +8 mod 16 == xor 8

template <int CTRL>
static __device__ __forceinline__ float dppx(float x) {
  return __int_as_float(
      __builtin_amdgcn_update_dpp(0, __float_as_int(x), CTRL, 0xF, 0xF, false));
}

// y[l] = x[l ^ 32]  (VALU pipe; convention verified on HW in crf5/crf6)
static __device__ __forceinline__ float swap32(float x, bool hiHalf) {
#if __has_builtin(__builtin_amdgcn_permlane32_swap)
  auto r = __builtin_amdgcn_permlane32_swap(__float_as_uint(x),
                                            __float_as_uint(x), false, false);
  return __uint_as_float(hiHalf ? r[0] : r[1]);
#else
  float a = x, b = x;
  asm("s_nop 1\n\ts_nop 1\n\tv_permlane32_swap_b32 %0, %1"
      : "+v"(a), "+v"(b));
  return hiHalf ? a : b;
#endif
}

// y[l] = x[l ^ 16]  (convention verified on HW in crf6)
static __device__ __forceinline__ float swap16(float x, bool hi16) {
#if __has_builtin(__builtin_amdgcn_permlane16_swap)
  auto r = __builtin_amdgcn_permlane16_swap(__float_as_uint(x),
                                            __float_as_uint(x), false, false);
  return __uint_as_float(hi16 ? r[0] : r[1]);
#else
  float a = x, b = x;
  asm("s_nop 1\n\ts_nop 1\n\tv_permlane16_swap_b32 %0, %1"
      : "+v"(a), "+v"(b));
  return hi16 ? a : b;
#endif
}

__global__ __launch_bounds__(64, 2) void crf7_kernel(
    const float* __restrict__ feats,
    const float* __restrict__ mask,
    const float* __restrict__ trans,
    float* __restrict__ out) {

  const int l   = threadIdx.x;
  const int t0  = l & 15;
  const int row = l >> 4;                      // 0..3
  const int i   = ((row & 1) << 4) | t0;       // tag (rows 2,3 duplicate 0,1)
  const int srcbase = (row == 1 || row == 2) ? 16 : 0;  // this lane's 16 sources
  const bool hi16   = (row & 1) != 0;          // lane bit4
  const bool hiHalf = (row & 2) != 0;          // lane bit5 (rows 2,3 use z)
  const int b = blockIdx.x;

  const float* fbase = feats + (size_t)b * TT + i;   // + s*BB*TT per step
  const float* mbase = mask + b;                     // + s*BB per step (uniform)
  const float t_stop = trans[30 * TT + i];           // trans[STOP_TAG][i]

  // 8-step prefetch in two 4-buffers; refills placed right after consumption.
  float fA[4], mA[4], fB[4], mB[4];
#pragma unroll
  for (int u = 0; u < 4; ++u) {
    fA[u] = fbase[(size_t)u * (BB * TT)];
    mA[u] = mbase[(size_t)u * BB];
    fB[u] = fbase[(size_t)(u + 4) * (BB * TT)];
    mB[u] = mbase[(size_t)(u + 4) * BB];
  }

  if (blockIdx.y == 0) {
    // ======================= forward (logZ) =======================
    float eT[16];
#pragma unroll
    for (int m = 0; m < 16; ++m)
      eT[m] = __expf(trans[i * TT + (srcbase | (t0 ^ m))]);  // exp(-1e4)==0

    float p   = (i == 29) ? 1.0f : 0.0f;   // exp(alpha0), START_TAG = 29
    int   CE  = 0;                         // exact pow2 rescale exponent sum
    float q0f = 1.0f;                      // lagged p[tag0] (any >0 valid)

    auto fstep = [&](float fv, float mv) {
      bool act = (mv != 0.0f);             // wave-uniform
      float ef = __expf(fv);               // off-chain (load-dependent only)
      // exact pow2 scale from lagged q0f's raw exponent: scale = 2^-(Eb-127)
      int Eb = (int)((__float_as_uint(q0f) >> 23) & 0xFFu);
      float scl = __uint_as_float((unsigned)(254 - Eb) << 23);
      float efs = ef * scl;
      float z = swap16(p, hi16);           // rows 2,3 source base
      float x = hiHalf ? z : p;
      // depth-2 gather hubs (one hop from x; values identical to crf6 slots)
      float r7  = dppx<DPP_RHMIR>(x);      // x ^ 7
      float r8  = dppx<DPP_ROR8>(x);       // x ^ 8 (ror:8, direction-immune)
      float r15 = dppx<DPP_RMIR>(x);       // x ^ 15
      // 16-source MAC; leaf permutes single-use -> fuse into v_fmac_dpp
      float a0 = eT[0] * x;
      float a1 = eT[1] * dppx<DPP_QX1>(x);
      float a2 = eT[2] * dppx<DPP_QX2>(x);
      float a3 = eT[3] * dppx<DPP_QX3>(x);
      a0 = fmaf(dppx<DPP_QX3>(r7),  eT[4],  a0);
      a1 = fmaf(dppx<DPP_QX2>(r7),  eT[5],  a1);
      a2 = fmaf(dppx<DPP_QX1>(r7),  eT[6],  a2);
      a3 = fmaf(r7,                 eT[7],  a3);
      a0 = fmaf(r8,                 eT[8],  a0);
      a1 = fmaf(dppx<DPP_QX1>(r8),  eT[9],  a1);
      a2 = fmaf(dppx<DPP_QX2>(r8),  eT[10], a2);
      a3 = fmaf(dppx<DPP_QX3>(r8),  eT[11], a3);
      a0 = fmaf(dppx<DPP_QX3>(r15), eT[12], a0);
      a1 = fmaf(dppx<DPP_QX2>(r15), eT[13], a1);
      a2 = fmaf(dppx<DPP_QX1>(r15), eT[14], a2);
      a3 = fmaf(r15,                eT[15], a3);
      float Dp = (a0 + a1) + (a2 + a3);    // partial over this lane's 16 srcs
      float Df = Dp + swap32(Dp, hiHalf);  // + complementary partial (l^32)
      float pn = Df * efs;
      p   = act ? pn : p;
      CE += act ? (Eb - 127) : 0;          // integer, exact (SALU)
      q0f = __uint_as_float(
          (unsigned)__builtin_amdgcn_readfirstlane((int)__float_as_uint(p)));
    };

#pragma unroll 1
    for (int s = 0; s < SS; s += 8) {
      if (mA[0] == 0.0f) goto fwd_done;    // uniform monotone mask
#pragma unroll
      for (int u = 0; u < 4; ++u) fstep(fA[u], mA[u]);
#pragma unroll
      for (int u = 0; u < 4; ++u) {        // refill A with s+8..s+11
        int su = s + 8 + u; su = (su < SS) ? su : 0;
        fA[u] = fbase[(size_t)su * (BB * TT)];
        mA[u] = mbase[(size_t)su * BB];
      }
      if (mB[0] == 0.0f) goto fwd_done;
#pragma unroll
      for (int u = 0; u < 4; ++u) fstep(fB[u], mB[u]);
#pragma unroll
      for (int u = 0; u < 4; ++u) {        // refill B with s+12..s+15
        int su = s + 12 + u; su = (su < SS) ? su : 0;
        fB[u] = fbase[(size_t)su * (BB * TT)];
        mB[u] = mbase[(size_t)su * BB];
      }
    }
fwd_done:
    {
      float alpha = (float)CE * 0.693147180559945f + __logf(p);  // p==0 -> -inf
      float v = alpha + t_stop;
      // lanes 0-31 hold all 32 tags (dup in 32-63): xor set {1,2,4,8,16}
      float M2 = v;
      M2 = fmaxf(M2, __shfl_xor(M2, 1, 64));
      M2 = fmaxf(M2, __shfl_xor(M2, 2, 64));
      M2 = fmaxf(M2, __shfl_xor(M2, 4, 64));
      M2 = fmaxf(M2, __shfl_xor(M2, 8, 64));
      M2 = fmaxf(M2, __shfl_xor(M2, 16, 64));
      float e = __expf(v - M2);
      e += __shfl_xor(e, 1, 64);
      e += __shfl_xor(e, 2, 64);
      e += __shfl_xor(e, 4, 64);
      e += __shfl_xor(e, 8, 64);
      e += __shfl_xor(e, 16, 64);
      if (l == 0) out[b] = M2 + __logf(e);
    }
    return;
  }

  // ========================= viterbi =========================
  {
    float tT[16];
    unsigned tg[16];
#pragma unroll
    for (int m = 0; m < 16; ++m) {
      int j = srcbase | (t0 ^ m);
      tT[m] = trans[i * TT + j];
      tg[m] = (unsigned)j;
    }

    float sc = (i == 29) ? 0.0f : -10000.0f;
    int s_exit = SS;
    float* outp = out + POFF + (size_t)b * TT + i;

    auto vstep = [&](float& best, int& ptr) {
      float z = swap16(sc, hi16);
      float x = hiHalf ? z : sc;
      float r7  = dppx<DPP_RHMIR>(x);
      float r8  = dppx<DPP_ROR8>(x);
      float r15 = dppx<DPP_RMIR>(x);
      float vv[16];
      // leaf permutes single-use -> fuse into v_add_f32_dpp
      vv[0]  = x + tT[0];
      vv[1]  = dppx<DPP_QX1>(x) + tT[1];
      vv[2]  = dppx<DPP_QX2>(x) + tT[2];
      vv[3]  = dppx<DPP_QX3>(x) + tT[3];
      vv[4]  = dppx<DPP_QX3>(r7) + tT[4];
      vv[5]  = dppx<DPP_QX2>(r7) + tT[5];
      vv[6]  = dppx<DPP_QX1>(r7) + tT[6];
      vv[7]  = r7 + tT[7];
      vv[8]  = r8 + tT[8];
      vv[9]  = dppx<DPP_QX1>(r8) + tT[9];
      vv[10] = dppx<DPP_QX2>(r8) + tT[10];
      vv[11] = dppx<DPP_QX3>(r8) + tT[11];
      vv[12] = dppx<DPP_QX3>(r15) + tT[12];
      vv[13] = dppx<DPP_QX2>(r15) + tT[13];
      vv[14] = dppx<DPP_QX1>(r15) + tT[14];
      vv[15] = r15 + tT[15];
      // exact max (3-ary nesting -> v_max3_f32)
      float g0 = fmaxf(fmaxf(vv[0], vv[1]), vv[2]);
      float g1 = fmaxf(fmaxf(vv[3], vv[4]), vv[5]);
      float g2 = fmaxf(fmaxf(vv[6], vv[7]), vv[8]);
      float g3 = fmaxf(fmaxf(vv[9], vv[10]), vv[11]);
      float g4 = fmaxf(fmaxf(vv[12], vv[13]), vv[14]);
      float h0 = fmaxf(fmaxf(g0, g1), g2);
      float h1 = fmaxf(fmaxf(g3, g4), vv[15]);
      float mxp = fmaxf(h0, h1);
      float mx  = fmaxf(mxp, swap32(mxp, hiHalf));  // global over 32 sources
      // leftmost argmax: min source-tag among exact-max matches (off-chain)
      unsigned k[16];
#pragma unroll
      for (int m = 0; m < 16; ++m) k[m] = (vv[m] == mx) ? tg[m] : 63u;
      unsigned n0 = min(min(k[0],  k[1]),  k[2]);   // -> v_min3_u32
      unsigned n1 = min(min(k[3],  k[4]),  k[5]);
      unsigned n2 = min(min(k[6],  k[7]),  k[8]);
      unsigned n3 = min(min(k[9],  k[10]), k[11]);
      unsigned n4 = min(min(k[12], k[13]), k[14]);
      unsigned p0 = min(min(n0, n1), n2);
      unsigned p1 = min(min(n3, n4), k[15]);
      int idx = (int)min(p0, p1);
      int oidx = __float_as_int(swap32(__int_as_float(idx), hiHalf));
      idx = (oidx < idx) ? oidx : idx;
      best = mx;
      ptr  = idx;
    };

#pragma unroll 1
    for (int s = 0; s < SS; s += 8) {
      if (mA[0] == 0.0f) { s_exit = s; goto vtail; }
#pragma unroll
      for (int u2 = 0; u2 < 4; ++u2) {
        float best; int ptr;
        vstep(best, ptr);
        if (l < 32) outp[(size_t)(s + u2) * (BB * TT)] = (float)ptr;
        sc = (mA[u2] != 0.0f) ? (best + fA[u2]) : sc;  // bit-exact vs numpy
      }
#pragma unroll
      for (int u2 = 0; u2 < 4; ++u2) {
        int su = s + 8 + u2; su = (su < SS) ? su : 0;
        fA[u2] = fbase[(size_t)su * (BB * TT)];
        mA[u2] = mbase[(size_t)su * BB];
      }
      if (mB[0] == 0.0f) { s_exit = s + 4; goto vtail; }
#pragma unroll
      for (int u2 = 0; u2 < 4; ++u2) {
        float best; int ptr;
        vstep(best, ptr);
        if (l < 32) outp[(size_t)(s + 4 + u2) * (BB * TT)] = (float)ptr;
        sc = (mB[u2] != 0.0f) ? (best + fB[u2]) : sc;
      }
#pragma unroll
      for (int u2 = 0; u2 < 4; ++u2) {
        int su = s + 12 + u2; su = (su < SS) ? su : 0;
        fB[u2] = fbase[(size_t)su * (BB * TT)];
        mB[u2] = mbase[(size_t)su * BB];
      }
    }
vtail:
    {
      // frozen scores -> constant ptr rows: compute once, store-only loop
      float tb; int tp;
      vstep(tb, tp);
      float tj = (float)tp;
      for (int s2 = s_exit; s2 < SS; ++s2)
        if (l < 32) outp[(size_t)s2 * (BB * TT)] = tj;

      float w = sc + t_stop;
      w = fmaxf(w, __shfl_xor(w, 1, 64));
      w = fmaxf(w, __shfl_xor(w, 2, 64));
      w = fmaxf(w, __shfl_xor(w, 4, 64));
      w = fmaxf(w, __shfl_xor(w, 8, 64));
      w = fmaxf(w, __shfl_xor(w, 16, 64));
      if (l == 0) out[BB + b] = w;
    }
  }
}

extern "C" void kernel_launch(void* const* d_in, const int* in_sizes, int n_in,
                              void* d_out, int out_size, void* d_ws, size_t ws_size,
                              hipStream_t stream) {
  const float* feats = (const float*)d_in[0];
  const float* msk   = (const float*)d_in[1];
  const float* trans = (const float*)d_in[2];
  float* out = (float*)d_out;
  (void)in_sizes; (void)n_in; (void)out_size; (void)d_ws; (void)ws_size;
  crf7_kernel<<<dim3(BB, 2), dim3(64), 0, stream>>>(feats, msk, trans, out);
}

// Round 5
// 547.678 us; speedup vs baseline: 1.2696x; 1.0246x over previous
//
#include <hip/hip_runtime.h>

// CRF forward (logZ) + Viterbi (best score + backpointers).
//
// Structure (r3/r4-verified): grid (B,2), one batch per wave, 2 waves/SIMD.
// Lanes: t0=l&15, row=l>>4; tag i=((row&1)<<4)|t0; rows 2,3 duplicate tags;
// srcbase: rows 0,3 sum sources 0-15, rows 1,2 sum 16-31; rows 2,3 take
// base from swap16; lane pair (l, l^32) merges complementary source halves
// via one permlane32_swap. Gather = depth-2 DPP xor tree (HW-verified).
//
// r4 post-mortem: wall/batch-step ~470 cy across LDS and DPP structures,
// invariant to a 30% VALU cut => NOT issue/chain-bound. 432 cy/step both-
// wave stall suspected on the per-step MASK machinery (wave-uniform mask
// loads scalarize to s_load -> K$-miss + lgkmcnt(0) drain per group).
// r5 change: NO mask in the loop. mask is monotone (length-coded):
//   * one-time 2-probe length find: lanes probe s=16*l (ballot/ffs ->
//     16-window W), then s=W+(l&15) (popcount -> len). 2 round trips.
//   * loop bound = len (scalar); no mask loads, no act cndmasks, no
//     ballots; prefetch wrap via su&1023; loads/group halved.
//   * tail (len&7) consumes already-prefetched fA/fB; vit frozen-pointer
//     tail unchanged (compute once, store-only loop).
// fwd rescale exact pow2 (raw exponent bits, integer CE); no rcp/log in
// loop. Viterbi value path bit-exact vs numpy (same adds, exact max tree,
// leftmost ties via min-tag among exact-max matches).

#define SS 1024
#define BB 1024
#define TT 32
#define POFF (2 * BB)   // pointers offset in d_out (after logZ, best_score)
#define STEP (BB * TT)  // floats per time-step plane

#define DPP_QX1   0xB1   // quad_perm [1,0,3,2] : xor 1
#define DPP_QX2   0x4E   // quad_perm [2,3,0,1] : xor 2
#define DPP_QX3   0x1B   // quad_perm [3,2,1,0] : xor 3
#define DPP_RMIR  0x140  // row_mirror        : xor 15 (within 16)
#define DPP_RHMIR 0x141  // row_half_mirror   : xor 7  (within 8)
#define DPP_ROR8  0x128  // row_ror:8         : +8 mod 16 == xor 8

template <int CTRL>
static __device__ __forceinline__ float dppx(float x) {
  return __int_as_float(
      __builtin_amdgcn_update_dpp(0, __float_as_int(x), CTRL, 0xF, 0xF, false));
}

// y[l] = x[l ^ 32]  (VALU pipe; convention HW-verified in crf5/6/7)
static __device__ __forceinline__ float swap32(float x, bool hiHalf) {
#if __has_builtin(__builtin_amdgcn_permlane32_swap)
  auto r = __builtin_amdgcn_permlane32_swap(__float_as_uint(x),
                                            __float_as_uint(x), false, false);
  return __uint_as_float(hiHalf ? r[0] : r[1]);
#else
  float a = x, b = x;
  asm("s_nop 1\n\ts_nop 1\n\tv_permlane32_swap_b32 %0, %1"
      : "+v"(a), "+v"(b));
  return hiHalf ? a : b;
#endif
}

// y[l] = x[l ^ 16]  (convention HW-verified in crf6/7)
static __device__ __forceinline__ float swap16(float x, bool hi16) {
#if __has_builtin(__builtin_amdgcn_permlane16_swap)
  auto r = __builtin_amdgcn_permlane16_swap(__float_as_uint(x),
                                            __float_as_uint(x), false, false);
  return __uint_as_float(hi16 ? r[0] : r[1]);
#else
  float a = x, b = x;
  asm("s_nop 1\n\ts_nop 1\n\tv_permlane16_swap_b32 %0, %1"
      : "+v"(a), "+v"(b));
  return hi16 ? a : b;
#endif
}

__global__ __launch_bounds__(64, 2) void crf8_kernel(
    const float* __restrict__ feats,
    const float* __restrict__ mask,
    const float* __restrict__ trans,
    float* __restrict__ out) {

  const int l   = threadIdx.x;
  const int t0  = l & 15;
  const int row = l >> 4;                      // 0..3
  const int i   = ((row & 1) << 4) | t0;       // tag (rows 2,3 duplicate 0,1)
  const int srcbase = (row == 1 || row == 2) ? 16 : 0;
  const bool hi16   = (row & 1) != 0;          // lane bit4
  const bool hiHalf = (row & 2) != 0;          // lane bit5 (rows 2,3 use z)
  const int b = blockIdx.x;

  const float* fbase = feats + (size_t)b * TT + i;   // + s*STEP per step
  const float t_stop = trans[30 * TT + i];           // trans[STOP_TAG][i]

  // Prefetch steps 0..7 (issued before the probe; independent of len).
  float fA[4], fB[4];
#pragma unroll
  for (int u = 0; u < 4; ++u) {
    fA[u] = fbase[(size_t)u * STEP];
    fB[u] = fbase[(size_t)(u + 4) * STEP];
  }

  // ---- one-time length probe over monotone mask[s][b], len in [512,1024].
  // Phase 1: lane l probes s=16*l; first-zero lane brackets a 16-window.
  // Phase 2: lanes 0-15 probe inside; popcount completes len. 2 round trips.
  int len;
  {
    float pr1 = mask[(size_t)(l << 4) * BB + b];
    unsigned long long m1 = __ballot(pr1 != 0.0f);
    unsigned long long nz = ~m1;
    int z1 = nz ? (__ffsll(nz) - 1) : 64;     // first zero probe lane
    int W = (z1 << 4) - 16;                   // window start (>= 496)
    float pr2 = mask[(size_t)(W + t0) * BB + b];
    unsigned long long m2 = __ballot(pr2 != 0.0f);
    len = W + __popcll(m2 & 0xFFFFull);
  }
  const int lim8 = len & ~7;                  // full 8-step groups
  const int rem  = len - lim8;                // 0..7 tail steps

  if (blockIdx.y == 0) {
    // ======================= forward (logZ) =======================
    float eT[16];
#pragma unroll
    for (int m = 0; m < 16; ++m)
      eT[m] = __expf(trans[i * TT + (srcbase | (t0 ^ m))]);  // exp(-1e4)==0

    float p   = (i == 29) ? 1.0f : 0.0f;   // exp(alpha0), START_TAG = 29
    int   CE  = 0;                         // exact pow2 rescale exponent sum
    float q0f = 1.0f;                      // lagged p[lane0] (any >0 valid)

    auto fstep = [&](float fv) {
      float ef = __expf(fv);               // off-chain (load-dependent only)
      int Eb = (int)((__float_as_uint(q0f) >> 23) & 0xFFu);
      float scl = __uint_as_float((unsigned)(254 - Eb) << 23);  // 2^-(Eb-127)
      float efs = ef * scl;
      float z = swap16(p, hi16);           // rows 2,3 source base
      float x = hiHalf ? z : p;
      float r7  = dppx<DPP_RHMIR>(x);      // depth-2 hubs
      float r8  = dppx<DPP_ROR8>(x);
      float r15 = dppx<DPP_RMIR>(x);
      float a0 = eT[0] * x;
      float a1 = eT[1] * dppx<DPP_QX1>(x);
      float a2 = eT[2] * dppx<DPP_QX2>(x);
      float a3 = eT[3] * dppx<DPP_QX3>(x);
      a0 = fmaf(dppx<DPP_QX3>(r7),  eT[4],  a0);
      a1 = fmaf(dppx<DPP_QX2>(r7),  eT[5],  a1);
      a2 = fmaf(dppx<DPP_QX1>(r7),  eT[6],  a2);
      a3 = fmaf(r7,                 eT[7],  a3);
      a0 = fmaf(r8,                 eT[8],  a0);
      a1 = fmaf(dppx<DPP_QX1>(r8),  eT[9],  a1);
      a2 = fmaf(dppx<DPP_QX2>(r8),  eT[10], a2);
      a3 = fmaf(dppx<DPP_QX3>(r8),  eT[11], a3);
      a0 = fmaf(dppx<DPP_QX3>(r15), eT[12], a0);
      a1 = fmaf(dppx<DPP_QX2>(r15), eT[13], a1);
      a2 = fmaf(dppx<DPP_QX1>(r15), eT[14], a2);
      a3 = fmaf(r15,                eT[15], a3);
      float Dp = (a0 + a1) + (a2 + a3);    // partial over this lane's 16 srcs
      float Df = Dp + swap32(Dp, hiHalf);  // + complementary partial (l^32)
      p = Df * efs;
      CE += Eb - 127;                      // integer, exact
      q0f = __uint_as_float(
          (unsigned)__builtin_amdgcn_readfirstlane((int)__float_as_uint(p)));
    };

#pragma unroll 1
    for (int s = 0; s < lim8; s += 8) {
      fstep(fA[0]); fstep(fA[1]); fstep(fA[2]); fstep(fA[3]);
#pragma unroll
      for (int u = 0; u < 4; ++u)
        fA[u] = fbase[(size_t)((s + 8 + u) & (SS - 1)) * STEP];
      fstep(fB[0]); fstep(fB[1]); fstep(fB[2]); fstep(fB[3]);
#pragma unroll
      for (int u = 0; u < 4; ++u)
        fB[u] = fbase[(size_t)((s + 12 + u) & (SS - 1)) * STEP];
    }
    // tail: rem in 0..7, data already prefetched in fA/fB (steps lim8..+7)
    if (rem > 0) fstep(fA[0]);
    if (rem > 1) fstep(fA[1]);
    if (rem > 2) fstep(fA[2]);
    if (rem > 3) fstep(fA[3]);
    if (rem > 4) fstep(fB[0]);
    if (rem > 5) fstep(fB[1]);
    if (rem > 6) fstep(fB[2]);
    {
      float alpha = (float)CE * 0.693147180559945f + __logf(p);  // p==0 -> -inf
      float v = alpha + t_stop;
      // lanes 0-31 hold all 32 tags (dup in 32-63): xor set {1,2,4,8,16}
      float M2 = v;
      M2 = fmaxf(M2, __shfl_xor(M2, 1, 64));
      M2 = fmaxf(M2, __shfl_xor(M2, 2, 64));
      M2 = fmaxf(M2, __shfl_xor(M2, 4, 64));
      M2 = fmaxf(M2, __shfl_xor(M2, 8, 64));
      M2 = fmaxf(M2, __shfl_xor(M2, 16, 64));
      float e = __expf(v - M2);
      e += __shfl_xor(e, 1, 64);
      e += __shfl_xor(e, 2, 64);
      e += __shfl_xor(e, 4, 64);
      e += __shfl_xor(e, 8, 64);
      e += __shfl_xor(e, 16, 64);
      if (l == 0) out[b] = M2 + __logf(e);
    }
    return;
  }

  // ========================= viterbi =========================
  {
    float tT[16];
    unsigned tg[16];
#pragma unroll
    for (int m = 0; m < 16; ++m) {
      int j = srcbase | (t0 ^ m);
      tT[m] = trans[i * TT + j];
      tg[m] = (unsigned)j;
    }

    float sc = (i == 29) ? 0.0f : -10000.0f;
    float* outp = out + POFF + (size_t)b * TT + i;

    auto vstep = [&](float& best, int& ptr) {
      float z = swap16(sc, hi16);
      float x = hiHalf ? z : sc;
      float r7  = dppx<DPP_RHMIR>(x);
      float r8  = dppx<DPP_ROR8>(x);
      float r15 = dppx<DPP_RMIR>(x);
      float vv[16];
      vv[0]  = x + tT[0];
      vv[1]  = dppx<DPP_QX1>(x) + tT[1];
      vv[2]  = dppx<DPP_QX2>(x) + tT[2];
      vv[3]  = dppx<DPP_QX3>(x) + tT[3];
      vv[4]  = dppx<DPP_QX3>(r7) + tT[4];
      vv[5]  = dppx<DPP_QX2>(r7) + tT[5];
      vv[6]  = dppx<DPP_QX1>(r7) + tT[6];
      vv[7]  = r7 + tT[7];
      vv[8]  = r8 + tT[8];
      vv[9]  = dppx<DPP_QX1>(r8) + tT[9];
      vv[10] = dppx<DPP_QX2>(r8) + tT[10];
      vv[11] = dppx<DPP_QX3>(r8) + tT[11];
      vv[12] = dppx<DPP_QX3>(r15) + tT[12];
      vv[13] = dppx<DPP_QX2>(r15) + tT[13];
      vv[14] = dppx<DPP_QX1>(r15) + tT[14];
      vv[15] = r15 + tT[15];
      // exact max (3-ary nesting -> v_max3_f32)
      float g0 = fmaxf(fmaxf(vv[0], vv[1]), vv[2]);
      float g1 = fmaxf(fmaxf(vv[3], vv[4]), vv[5]);
      float g2 = fmaxf(fmaxf(vv[6], vv[7]), vv[8]);
      float g3 = fmaxf(fmaxf(vv[9], vv[10]), vv[11]);
      float g4 = fmaxf(fmaxf(vv[12], vv[13]), vv[14]);
      float h0 = fmaxf(fmaxf(g0, g1), g2);
      float h1 = fmaxf(fmaxf(g3, g4), vv[15]);
      float mxp = fmaxf(h0, h1);
      float mx  = fmaxf(mxp, swap32(mxp, hiHalf));  // global over 32 sources
      // leftmost argmax: min source-tag among exact-max matches (off-chain)
      unsigned k[16];
#pragma unroll
      for (int m = 0; m < 16; ++m) k[m] = (vv[m] == mx) ? tg[m] : 63u;
      unsigned n0 = min(min(k[0],  k[1]),  k[2]);   // -> v_min3_u32
      unsigned n1 = min(min(k[3],  k[4]),  k[5]);
      unsigned n2 = min(min(k[6],  k[7]),  k[8]);
      unsigned n3 = min(min(k[9],  k[10]), k[11]);
      unsigned n4 = min(min(k[12], k[13]), k[14]);
      unsigned p0 = min(min(n0, n1), n2);
      unsigned p1 = min(min(n3, n4), k[15]);
      int idx = (int)min(p0, p1);
      int oidx = __float_as_int(swap32(__int_as_float(idx), hiHalf));
      idx = (oidx < idx) ? oidx : idx;
      best = mx;
      ptr  = idx;
    };

#pragma unroll 1
    for (int s = 0; s < lim8; s += 8) {
#pragma unroll
      for (int u2 = 0; u2 < 4; ++u2) {
        float best; int ptr;
        vstep(best, ptr);
        if (l < 32) outp[(size_t)(s + u2) * STEP] = (float)ptr;
        sc = best + fA[u2];                 // bit-exact vs numpy
      }
#pragma unroll
      for (int u2 = 0; u2 < 4; ++u2)
        fA[u2] = fbase[(size_t)((s + 8 + u2) & (SS - 1)) * STEP];
#pragma unroll
      for (int u2 = 0; u2 < 4; ++u2) {
        float best; int ptr;
        vstep(best, ptr);
        if (l < 32) outp[(size_t)(s + 4 + u2) * STEP] = (float)ptr;
        sc = best + fB[u2];
      }
#pragma unroll
      for (int u2 = 0; u2 < 4; ++u2)
        fB[u2] = fbase[(size_t)((s + 12 + u2) & (SS - 1)) * STEP];
    }
    // tail steps lim8..len-1 (data already in fA/fB)
    {
      float tf[7] = {fA[0], fA[1], fA[2], fA[3], fB[0], fB[1], fB[2]};
#pragma unroll 1
      for (int k2 = 0; k2 < rem; ++k2) {
        float best; int ptr;
        vstep(best, ptr);
        if (l < 32) outp[(size_t)(lim8 + k2) * STEP] = (float)ptr;
        sc = best + tf[k2];
      }
    }
    {
      // frozen scores -> constant ptr rows: compute once, store-only loop
      float tb; int tp;
      vstep(tb, tp);
      float tj = (float)tp;
#pragma unroll 1
      for (int s2 = len; s2 < SS; ++s2)
        if (l < 32) outp[(size_t)s2 * STEP] = tj;

      float w = sc + t_stop;
      w = fmaxf(w, __shfl_xor(w, 1, 64));
      w = fmaxf(w, __shfl_xor(w, 2, 64));
      w = fmaxf(w, __shfl_xor(w, 4, 64));
      w = fmaxf(w, __shfl_xor(w, 8, 64));
      w = fmaxf(w, __shfl_xor(w, 16, 64));
      if (l == 0) out[BB + b] = w;
    }
  }
}

extern "C" void kernel_launch(void* const* d_in, const int* in_sizes, int n_in,
                              void* d_out, int out_size, void* d_ws, size_t ws_size,
                              hipStream_t stream) {
  const float* feats = (const float*)d_in[0];
  const float* msk   = (const float*)d_in[1];
  const float* trans = (const float*)d_in[2];
  float* out = (float*)d_out;
  (void)in_sizes; (void)n_in; (void)out_size; (void)d_ws; (void)ws_size;
  crf8_kernel<<<dim3(BB, 2), dim3(64), 0, stream>>>(feats, msk, trans, out);
}